// Round 1
// baseline (95.656 us; speedup 1.0000x reference)
//
#include <hip/hip_runtime.h>

#define TRAIN_ROIS 256
#define POS_QUOTA 25          // int(0.1 * 256)
#define POS_THR 0.5f
#define NEG_THR 0.02f
#define EPS 1e-8f

// IoU with arithmetic mirroring the reference exactly (left-assoc products,
// (v1+v2)-inter+eps denominator). Pure mul/sub/div/max: no FMA-contraction
// ambiguity, so recomputation is bit-identical across kernels.
__device__ __forceinline__ float iou3d(const float* __restrict__ g,
                                       const float* __restrict__ b) {
    float lo0 = fmaxf(g[0], b[0]);
    float lo1 = fmaxf(g[1], b[1]);
    float lo2 = fmaxf(g[2], b[2]);
    float hi0 = fminf(g[3], b[3]);
    float hi1 = fminf(g[4], b[4]);
    float hi2 = fminf(g[5], b[5]);
    float d0 = fmaxf(hi0 - lo0, 0.0f);
    float d1 = fmaxf(hi1 - lo1, 0.0f);
    float d2 = fmaxf(hi2 - lo2, 0.0f);
    float inter = (d0 * d1) * d2;
    float v1 = ((g[3] - g[0]) * (g[4] - g[1])) * (g[5] - g[2]);
    float v2 = ((b[3] - b[0]) * (b[4] - b[1])) * (b[5] - b[2]);
    return inter / (((v1 + v2) - inter) + EPS);
}

// Phase A: per (image,proposal) compute max IoU over G gts; emit tie bitmasks
// (bit g set iff iou_g == max) classified pos (max>=0.5) or neg (max<0.02).
// Also zero-inits orders and per-g counters (ws is poisoned).
__global__ void phaseA(const float* __restrict__ props, const int* __restrict__ bidx,
                       const float* __restrict__ gtb,
                       unsigned int* __restrict__ posBits, unsigned int* __restrict__ negBits,
                       int* __restrict__ orders, int* __restrict__ gcnt,
                       int P, int B, int G) {
    int gid = blockIdx.x * blockDim.x + threadIdx.x;
    if (gid < B * 2 * TRAIN_ROIS) orders[gid] = 0;
    if (gid < B * 2 * G) gcnt[gid] = 0;
    if (gid >= B * P) return;
    int i = gid / P;
    int p = gid - i * P;
    unsigned int pb = 0, nb = 0;
    if (bidx[p] == i) {
        float b[6];
#pragma unroll
        for (int k = 0; k < 6; ++k) b[k] = props[p * 6 + k];
        const float* gbase = gtb + (size_t)i * G * 6;
        float m = -1e30f;
        for (int g = 0; g < G; ++g) m = fmaxf(m, iou3d(gbase + g * 6, b));
        if (m >= POS_THR) {
            for (int g = 0; g < G; ++g)
                if (iou3d(gbase + g * 6, b) == m) pb |= 1u << g;
        } else if (m < NEG_THR) {  // m >= 0 always for in-image proposals
            for (int g = 0; g < G; ++g)
                if (iou3d(gbase + g * 6, b) == m) nb |= 1u << g;
        }
    }
    posBits[gid] = pb;
    negBits[gid] = nb;
}

// Phase B1: count set bits per (image, type, g). Requires P % blockDim == 0
// (P=65536, blockDim=1024) so each block sits inside one image.
__launch_bounds__(1024)
__global__ void countKernel(const unsigned int* __restrict__ posBits,
                            const unsigned int* __restrict__ negBits,
                            int* __restrict__ gcnt, int P, int G) {
    __shared__ int sc[2 * 64];
    int tid = threadIdx.x;
    int gid = blockIdx.x * blockDim.x + tid;
    int i = gid / P;
    for (int t = tid; t < 2 * G; t += blockDim.x) sc[t] = 0;
    __syncthreads();
    unsigned int pb = posBits[gid], nb = negBits[gid];
    while (pb) { int g = __ffs(pb) - 1; pb &= pb - 1; atomicAdd(&sc[g], 1); }
    while (nb) { int g = __ffs(nb) - 1; nb &= nb - 1; atomicAdd(&sc[G + g], 1); }
    __syncthreads();
    for (int t = tid; t < 2 * G; t += blockDim.x)
        if (sc[t]) atomicAdd(&gcnt[i * 2 * G + t], sc[t]);
}

// Phase B2: exclusive prefix over g per (image,type); totals capped at 256.
__global__ void prefixKernel(const int* __restrict__ gcnt, int* __restrict__ goff,
                             int* __restrict__ totals, int B, int G) {
    int t = threadIdx.x;  // (i,type) pair
    if (t >= B * 2) return;
    const int* c = gcnt + t * G;
    int* o = goff + t * G;
    int run = 0;
    for (int g = 0; g < G; ++g) { o[g] = run; run += c[g]; }
    totals[t] = run < TRAIN_ROIS ? run : TRAIN_ROIS;
}

// Phase B3: per (image,type,g) block, ordered fill of order slots
// [off, min(off+cnt, 256)). Block-wide ordered rank via ballot + wave prefix.
__launch_bounds__(1024)
__global__ void fillKernel(const unsigned int* __restrict__ posBits,
                           const unsigned int* __restrict__ negBits,
                           const int* __restrict__ gcnt, const int* __restrict__ goff,
                           int* __restrict__ orders, int P, int G) {
    int bid = blockIdx.x;
    int g = bid % G;
    int it = bid / G;           // i*2 + type
    int type = it & 1;
    int i = it >> 1;
    int off = goff[it * G + g];
    int cnt = gcnt[it * G + g];
    int need = TRAIN_ROIS - off;
    if (cnt < need) need = cnt;
    if (need <= 0) return;
    const unsigned int* bits = (type ? negBits : posBits) + (size_t)i * P;
    int* order = orders + it * TRAIN_ROIS + off;
    __shared__ int wcnt[16];
    __shared__ int wpre[16];
    __shared__ int stotal;
    int tid = threadIdx.x, lane = tid & 63, wid = tid >> 6;
    int base = 0;
    for (int p0 = 0; p0 < P && base < need; p0 += 1024) {
        int p = p0 + tid;
        bool bit = (bits[p] >> g) & 1u;
        unsigned long long bal = __ballot(bit);
        int laneRank = __popcll(bal & ((1ull << lane) - 1ull));
        if (lane == 0) wcnt[wid] = __popcll(bal);
        __syncthreads();
        if (tid == 0) {
            int run = 0;
            for (int w = 0; w < 16; ++w) { wpre[w] = run; run += wcnt[w]; }
            stotal = run;
        }
        __syncthreads();
        if (bit) {
            int r = base + wpre[wid] + laneRank;
            if (r < need) order[r] = g * P + p;
        }
        base += stotal;
    }
}

// Phase C: emit all outputs. out layout: rois[B*256*6] | deltas[B*256*6] |
// labels[B*256] | tag[B*256] | ridx[B*256], all as float32.
__global__ void phaseC(const float* __restrict__ props, const float* __restrict__ gtb,
                       const int* __restrict__ glab,
                       const int* __restrict__ orders, const int* __restrict__ totals,
                       float* __restrict__ out, int P, int G, int B) {
    int i = blockIdx.x;
    int s = threadIdx.x;
    int pos_cnt = totals[2 * i + 0];
    int neg_cnt = totals[2 * i + 1];
    int pos_num = pos_cnt < POS_QUOTA ? pos_cnt : POS_QUOTA;
    int rem = TRAIN_ROIS - pos_num;
    int neg_num = neg_cnt < rem ? neg_cnt : rem;
    bool is_pos = s < pos_num;
    bool valid = s < pos_num + neg_num;
    int t = s - pos_num;
    t = t < 0 ? 0 : (t > TRAIN_ROIS - 1 ? TRAIN_ROIS - 1 : t);
    int idx = is_pos ? orders[(2 * i + 0) * TRAIN_ROIS + s]
                     : orders[(2 * i + 1) * TRAIN_ROIS + t];
    int g = idx / P;
    int p = idx - g * P;
    float b[6], gt[6];
#pragma unroll
    for (int k = 0; k < 6; ++k) {
        b[k] = props[p * 6 + k];
        gt[k] = gtb[((size_t)i * G + g) * 6 + k];
    }
    float vf = valid ? 1.0f : 0.0f;
    int row = i * TRAIN_ROIS + s;
    float* o_rois = out;
    float* o_del = out + (size_t)B * TRAIN_ROIS * 6;
    float* o_lab = o_del + (size_t)B * TRAIN_ROIS * 6;
    float* o_tag = o_lab + (size_t)B * TRAIN_ROIS;
    float* o_ridx = o_tag + (size_t)B * TRAIN_ROIS;
#pragma unroll
    for (int k = 0; k < 6; ++k) o_rois[row * 6 + k] = b[k] * vf;
    float sz0 = b[3] - b[0], sz1 = b[4] - b[1], sz2 = b[5] - b[2];
    float c0 = (b[0] + b[3]) * 0.5f, c1 = (b[1] + b[4]) * 0.5f, c2 = (b[2] + b[5]) * 0.5f;
    float gs0 = gt[3] - gt[0], gs1 = gt[4] - gt[1], gs2 = gt[5] - gt[2];
    float gc0 = (gt[0] + gt[3]) * 0.5f, gc1 = (gt[1] + gt[4]) * 0.5f, gc2 = (gt[2] + gt[5]) * 0.5f;
    float d[6];
    d[0] = (gc0 - c0) / sz0;
    d[1] = (gc1 - c1) / sz1;
    d[2] = (gc2 - c2) / sz2;
    d[3] = logf(gs0 / sz0);
    d[4] = logf(gs1 / sz1);
    d[5] = logf(gs2 / sz2);
#pragma unroll
    for (int k = 0; k < 6; ++k) o_del[row * 6 + k] = d[k] * vf;
    int lab = is_pos ? glab[i * G + g] : 0;
    o_lab[row] = (float)(valid ? lab : 0);
    o_tag[row] = is_pos ? 1.0f : (valid ? -1.0f : 0.0f);
    o_ridx[row] = valid ? (float)i : -1.0f;
}

extern "C" void kernel_launch(void* const* d_in, const int* in_sizes, int n_in,
                              void* d_out, int out_size, void* d_ws, size_t ws_size,
                              hipStream_t stream) {
    const float* props = (const float*)d_in[0];
    const int* bidx = (const int*)d_in[1];
    const float* gtb = (const float*)d_in[2];
    const int* glab = (const int*)d_in[3];
    int P = in_sizes[1];                       // 65536
    int B = out_size / (TRAIN_ROIS * 15);      // 6+6+1+1+1 per slot -> 8
    int G = in_sizes[3] / B;                   // 32

    unsigned int* posBits = (unsigned int*)d_ws;
    unsigned int* negBits = posBits + (size_t)B * P;
    int* orders = (int*)(negBits + (size_t)B * P);   // [B][2][256]
    int* gcnt = orders + B * 2 * TRAIN_ROIS;         // [B][2][G]
    int* goff = gcnt + B * 2 * G;                    // [B][2][G]
    int* totals = goff + B * 2 * G;                  // [B][2]

    int total = B * P;
    phaseA<<<(total + 255) / 256, 256, 0, stream>>>(props, bidx, gtb, posBits, negBits,
                                                    orders, gcnt, P, B, G);
    countKernel<<<total / 1024, 1024, 0, stream>>>(posBits, negBits, gcnt, P, G);
    prefixKernel<<<1, 64, 0, stream>>>(gcnt, goff, totals, B, G);
    fillKernel<<<B * 2 * G, 1024, 0, stream>>>(posBits, negBits, gcnt, goff, orders, P, G);
    phaseC<<<B, TRAIN_ROIS, 0, stream>>>(props, gtb, glab, orders, totals,
                                         (float*)d_out, P, G, B);
}

// Round 2
// 67.628 us; speedup vs baseline: 1.4144x; 1.4144x over previous
//
#include <hip/hip_runtime.h>

#define TRAIN_ROIS 256
#define POS_QUOTA 25          // int(0.1 * 256)
#define POS_THR 0.5f
#define NEG_THR 0.02f
#define EPS 1e-8f
#define G_MAX 32
#define B_MAX 16

// IoU with arithmetic mirroring the reference exactly (left-assoc products,
// (v1+v2)-inter+eps denominator). Pure mul/sub/div/max: no FMA-contraction
// ambiguity, so recomputation is bit-identical across kernels.
__device__ __forceinline__ float iou3d(const float* __restrict__ g,
                                       const float* __restrict__ b) {
    float lo0 = fmaxf(g[0], b[0]);
    float lo1 = fmaxf(g[1], b[1]);
    float lo2 = fmaxf(g[2], b[2]);
    float hi0 = fminf(g[3], b[3]);
    float hi1 = fminf(g[4], b[4]);
    float hi2 = fminf(g[5], b[5]);
    float d0 = fmaxf(hi0 - lo0, 0.0f);
    float d1 = fmaxf(hi1 - lo1, 0.0f);
    float d2 = fmaxf(hi2 - lo2, 0.0f);
    float inter = (d0 * d1) * d2;
    float v1 = ((g[3] - g[0]) * (g[4] - g[1])) * (g[5] - g[2]);
    float v2 = ((b[3] - b[0]) * (b[4] - b[1])) * (b[5] - b[2]);
    return inter / (((v1 + v2) - inter) + EPS);
}

// Phase A: one thread per proposal. Compute max IoU over the G gts of its own
// image, emit tie bitmask classified pos/neg, and accumulate per-(image,type,g)
// counts via LDS. Full masks (all-G ties, the common iou==0 neg case) are
// counted separately with a single atomic.
__global__ void phaseA(const float* __restrict__ props, const int* __restrict__ bidx,
                       const float* __restrict__ gtb,
                       unsigned int* __restrict__ posBits, unsigned int* __restrict__ negBits,
                       int* __restrict__ gcntPart, int* __restrict__ gcntFull,
                       int P, int B, int G) {
    __shared__ int sc[B_MAX * 2 * G_MAX];
    __shared__ int scFull[B_MAX * 2];
    int tid = threadIdx.x;
    int p = blockIdx.x * blockDim.x + tid;
    int nSlots = B * 2 * G;
    for (int t = tid; t < nSlots; t += blockDim.x) sc[t] = 0;
    for (int t = tid; t < B * 2; t += blockDim.x) scFull[t] = 0;
    __syncthreads();

    int i = 0;
    unsigned int pb = 0, nb = 0;
    bool active = p < P;
    if (active) {
        i = bidx[p];
        float b[6];
#pragma unroll
        for (int k = 0; k < 6; ++k) b[k] = props[p * 6 + k];
        const float* gbase = gtb + (size_t)i * G * 6;
        float iou[G_MAX];
        float m = -1e30f;
#pragma unroll
        for (int g = 0; g < G_MAX; ++g) {
            if (g < G) {
                iou[g] = iou3d(gbase + g * 6, b);
                m = fmaxf(m, iou[g]);
            } else {
                iou[g] = -2.0f;
            }
        }
        if (m >= POS_THR) {
#pragma unroll
            for (int g = 0; g < G_MAX; ++g)
                if (iou[g] == m) pb |= 1u << g;
        } else if (m < NEG_THR) {  // m >= 0 always for in-image proposals
#pragma unroll
            for (int g = 0; g < G_MAX; ++g)
                if (iou[g] == m) nb |= 1u << g;
        }
        posBits[p] = pb;
        negBits[p] = nb;
        unsigned int fullMask = (G >= 32) ? 0xFFFFFFFFu : ((1u << G) - 1u);
        if (pb) {
            if (pb == fullMask) atomicAdd(&scFull[i * 2 + 0], 1);
            else {
                unsigned int t = pb;
                while (t) { int g = __ffs(t) - 1; t &= t - 1; atomicAdd(&sc[(i * 2 + 0) * G + g], 1); }
            }
        }
        if (nb) {
            if (nb == fullMask) atomicAdd(&scFull[i * 2 + 1], 1);
            else {
                unsigned int t = nb;
                while (t) { int g = __ffs(t) - 1; t &= t - 1; atomicAdd(&sc[(i * 2 + 1) * G + g], 1); }
            }
        }
    }
    __syncthreads();
    for (int t = tid; t < nSlots; t += blockDim.x)
        if (sc[t]) atomicAdd(&gcntPart[t], sc[t]);
    for (int t = tid; t < B * 2; t += blockDim.x)
        if (scFull[t]) atomicAdd(&gcntFull[t], scFull[t]);
}

// Phase B: per (image,type,g) block. Computes its own exclusive prefix over g
// (count[g'] = part[g'] + full), then ordered-fills order slots
// [off, min(off+cnt,256)) with ascending p via ballot + wave prefix.
__launch_bounds__(1024)
__global__ void fillKernel(const unsigned int* __restrict__ posBits,
                           const unsigned int* __restrict__ negBits,
                           const int* __restrict__ bidx,
                           const int* __restrict__ gcntPart, const int* __restrict__ gcntFull,
                           int* __restrict__ orders, int P, int G) {
    int bid = blockIdx.x;
    int g = bid % G;
    int it = bid / G;           // i*2 + type
    int type = it & 1;
    int i = it >> 1;
    int full = gcntFull[it];
    int off = 0;
    for (int gg = 0; gg < g; ++gg) off += gcntPart[it * G + gg] + full;
    if (off >= TRAIN_ROIS) return;
    int cnt = gcntPart[it * G + g] + full;
    int need = TRAIN_ROIS - off;
    if (cnt < need) need = cnt;
    if (need <= 0) return;

    const unsigned int* bits = type ? negBits : posBits;
    int* order = orders + it * TRAIN_ROIS + off;
    __shared__ int wcnt[16];
    __shared__ int wpre[16];
    __shared__ int stotal;
    int tid = threadIdx.x, lane = tid & 63, wid = tid >> 6;
    int base = 0;
    for (int p0 = 0; p0 < P && base < need; p0 += 1024) {
        int p = p0 + tid;
        bool bit = (bidx[p] == i) && ((bits[p] >> g) & 1u);
        unsigned long long bal = __ballot(bit);
        int laneRank = __popcll(bal & ((1ull << lane) - 1ull));
        if (lane == 0) wcnt[wid] = __popcll(bal);
        __syncthreads();
        if (tid == 0) {
            int run = 0;
            for (int w = 0; w < 16; ++w) { wpre[w] = run; run += wcnt[w]; }
            stotal = run;
        }
        __syncthreads();
        if (bit) {
            int r = base + wpre[wid] + laneRank;
            if (r < need) order[r] = g * P + p;
        }
        base += stotal;
    }
}

// Phase C: emit all outputs. out layout: rois[B*256*6] | deltas[B*256*6] |
// labels[B*256] | tag[B*256] | ridx[B*256], all as float32. Totals computed
// in-block from the (capped-sufficient) counts.
__global__ void phaseC(const float* __restrict__ props, const float* __restrict__ gtb,
                       const int* __restrict__ glab,
                       const int* __restrict__ orders,
                       const int* __restrict__ gcntPart, const int* __restrict__ gcntFull,
                       float* __restrict__ out, int P, int G, int B) {
    __shared__ int s_pos_num, s_valid_num;
    int i = blockIdx.x;
    int s = threadIdx.x;
    if (s == 0) {
        int pos_total = 0, neg_total = 0;
        for (int g = 0; g < G; ++g) {
            pos_total += gcntPart[(2 * i + 0) * G + g];
            neg_total += gcntPart[(2 * i + 1) * G + g];
        }
        pos_total += G * gcntFull[2 * i + 0];
        neg_total += G * gcntFull[2 * i + 1];
        if (pos_total > TRAIN_ROIS) pos_total = TRAIN_ROIS;
        if (neg_total > TRAIN_ROIS) neg_total = TRAIN_ROIS;
        int pos_num = pos_total < POS_QUOTA ? pos_total : POS_QUOTA;
        int rem = TRAIN_ROIS - pos_num;
        int neg_num = neg_total < rem ? neg_total : rem;
        s_pos_num = pos_num;
        s_valid_num = pos_num + neg_num;
    }
    __syncthreads();
    int pos_num = s_pos_num;
    bool is_pos = s < pos_num;
    bool valid = s < s_valid_num;
    int t = s - pos_num;
    t = t < 0 ? 0 : (t > TRAIN_ROIS - 1 ? TRAIN_ROIS - 1 : t);
    int idx = is_pos ? orders[(2 * i + 0) * TRAIN_ROIS + s]
                     : orders[(2 * i + 1) * TRAIN_ROIS + t];
    int g = idx / P;
    int p = idx - g * P;
    float b[6], gt[6];
#pragma unroll
    for (int k = 0; k < 6; ++k) {
        b[k] = props[p * 6 + k];
        gt[k] = gtb[((size_t)i * G + g) * 6 + k];
    }
    float vf = valid ? 1.0f : 0.0f;
    int row = i * TRAIN_ROIS + s;
    float* o_rois = out;
    float* o_del = out + (size_t)B * TRAIN_ROIS * 6;
    float* o_lab = o_del + (size_t)B * TRAIN_ROIS * 6;
    float* o_tag = o_lab + (size_t)B * TRAIN_ROIS;
    float* o_ridx = o_tag + (size_t)B * TRAIN_ROIS;
#pragma unroll
    for (int k = 0; k < 6; ++k) o_rois[row * 6 + k] = b[k] * vf;
    float sz0 = b[3] - b[0], sz1 = b[4] - b[1], sz2 = b[5] - b[2];
    float c0 = (b[0] + b[3]) * 0.5f, c1 = (b[1] + b[4]) * 0.5f, c2 = (b[2] + b[5]) * 0.5f;
    float gs0 = gt[3] - gt[0], gs1 = gt[4] - gt[1], gs2 = gt[5] - gt[2];
    float gc0 = (gt[0] + gt[3]) * 0.5f, gc1 = (gt[1] + gt[4]) * 0.5f, gc2 = (gt[2] + gt[5]) * 0.5f;
    float d[6];
    d[0] = (gc0 - c0) / sz0;
    d[1] = (gc1 - c1) / sz1;
    d[2] = (gc2 - c2) / sz2;
    d[3] = logf(gs0 / sz0);
    d[4] = logf(gs1 / sz1);
    d[5] = logf(gs2 / sz2);
#pragma unroll
    for (int k = 0; k < 6; ++k) o_del[row * 6 + k] = d[k] * vf;
    int lab = is_pos ? glab[i * G + g] : 0;
    o_lab[row] = (float)(valid ? lab : 0);
    o_tag[row] = is_pos ? 1.0f : (valid ? -1.0f : 0.0f);
    o_ridx[row] = valid ? (float)i : -1.0f;
}

extern "C" void kernel_launch(void* const* d_in, const int* in_sizes, int n_in,
                              void* d_out, int out_size, void* d_ws, size_t ws_size,
                              hipStream_t stream) {
    const float* props = (const float*)d_in[0];
    const int* bidx = (const int*)d_in[1];
    const float* gtb = (const float*)d_in[2];
    const int* glab = (const int*)d_in[3];
    int P = in_sizes[1];                       // 65536
    int B = out_size / (TRAIN_ROIS * 15);      // 6+6+1+1+1 per slot -> 8
    int G = in_sizes[3] / B;                   // 32

    unsigned int* posBits = (unsigned int*)d_ws;      // [P]
    unsigned int* negBits = posBits + (size_t)P;      // [P]
    int* orders = (int*)(negBits + (size_t)P);        // [B][2][256]
    int* gcntPart = orders + B * 2 * TRAIN_ROIS;      // [B][2][G]
    int* gcntFull = gcntPart + B * 2 * G;             // [B][2]

    // zero orders + counters in one memset node (orders must be 0 so that
    // invalid-slot gathers in phaseC stay in-bounds; counters feed atomics)
    size_t zeroBytes = (size_t)(B * 2 * TRAIN_ROIS + B * 2 * G + B * 2) * sizeof(int);
    hipMemsetAsync(orders, 0, zeroBytes, stream);

    phaseA<<<(P + 255) / 256, 256, 0, stream>>>(props, bidx, gtb, posBits, negBits,
                                                gcntPart, gcntFull, P, B, G);
    fillKernel<<<B * 2 * G, 1024, 0, stream>>>(posBits, negBits, bidx,
                                               gcntPart, gcntFull, orders, P, G);
    phaseC<<<B, TRAIN_ROIS, 0, stream>>>(props, gtb, glab, orders,
                                         gcntPart, gcntFull, (float*)d_out, P, G, B);
}